// Round 8
// baseline (273.955 us; speedup 1.0000x reference)
//
#include <hip/hip_runtime.h>
#include <cfloat>

#define BB 32
#define AA 8400
#define GG 40
#define NC 80
#define NO 85
#define CAP 2048    // >= geometric bound ~27 anchors/gt * 40 gts = 1080
#define CAPW 13312  // >= 1280 gts * dk_max 10 = 12800
#define POISON 0xAAAAAAAAu
#define NF4 ((BB * AA * NO) / 4)   // 5,712,000 float4s in outputs

typedef unsigned long long ull;
#define U64MAX 0xFFFFFFFFFFFFFFFFull

// ---------- deterministic helpers: explicit _rn ops (no FMA contraction) so every
// call site produces bitwise-identical values ----------

__device__ inline bool dev_in(float gx, float gy, float xc, float yc, float r)
{
    float dl = __fsub_rn(xc, __fsub_rn(gx, r));
    float dr = __fsub_rn(__fadd_rn(gx, r), xc);
    float dt = __fsub_rn(yc, __fsub_rn(gy, r));
    float db = __fsub_rn(__fadd_rn(gy, r), yc);
    return fminf(fminf(dl, dr), fminf(dt, db)) > 0.0f;
}

__device__ inline float2 cost_iou(float gx, float gy, float gw, float gh,
                                  float px, float py, float pw, float ph,
                                  float xc, float yc, float r,
                                  float ct, float fg)
{
    bool in = dev_in(gx, gy, xc, yc, r);
    float gw2 = __fmul_rn(gw, 0.5f), gh2 = __fmul_rn(gh, 0.5f);
    float pw2 = __fmul_rn(pw, 0.5f), ph2 = __fmul_rn(ph, 0.5f);
    float tlx = fmaxf(__fsub_rn(gx, gw2), __fsub_rn(px, pw2));
    float tly = fmaxf(__fsub_rn(gy, gh2), __fsub_rn(py, ph2));
    float brx = fminf(__fadd_rn(gx, gw2), __fadd_rn(px, pw2));
    float bry = fminf(__fadd_rn(gy, gh2), __fadd_rn(py, ph2));
    float en = (tlx < brx && tly < bry) ? 1.0f : 0.0f;
    float ai = __fmul_rn(__fmul_rn(__fsub_rn(brx, tlx), __fsub_rn(bry, tly)), en);
    float ag = __fmul_rn(gw, gh);
    float ap = __fmul_rn(pw, ph);
    float iou = ai / __fsub_rn(__fadd_rn(ag, ap), ai);
    iou = (fg != 0.0f) ? iou : 0.0f;
    float icost = -__logf(__fadd_rn(iou, 1e-8f));
    float cost = __fadd_rn(__fadd_rn(ct, __fmul_rn(3.0f, icost)), in ? 0.0f : 1000000.0f);
    cost = (fg != 0.0f) ? cost : 1000000000.0f;
    return make_float2(cost, iou);
}

__device__ inline float softplus_bce(float x)
{
    return fmaxf(x, 0.0f) + __logf(1.0f + __expf(-fabsf(x)));
}

__device__ inline float wave_sum(float v)
{
#pragma unroll
    for (int o = 32; o > 0; o >>= 1) v += __shfl_down(v, o, 64);
    return v;
}

__device__ inline ull wave_min_u64(ull v)
{
#pragma unroll
    for (int o = 1; o < 64; o <<= 1) {
        ull w = (ull)__shfl_xor((long long)v, o, 64);
        v = w < v ? w : v;
    }
    return v;
}

__device__ inline float wave_max_f(float v)
{
#pragma unroll
    for (int o = 1; o < 64; o <<= 1) v = fmaxf(v, __shfl_xor(v, o, 64));
    return v;
}

// ctrl layout (ints): [0..7]=acc(float), [8..39]=cnt[32], [40]=wlcnt, [41]=fin

// ---------- K1a: ctrl init + matchcnt zero + fg compaction + coalesced obj-BCE scan ----
__global__ __launch_bounds__(256) void k1a_fg(
    const float* __restrict__ outputs, const float* __restrict__ labels,
    const float* __restrict__ xs_, const float* __restrict__ ys_, const float* __restrict__ st_,
    int* __restrict__ ctrl, int* __restrict__ matchcnt, int* __restrict__ alist)
{
    __shared__ float lgt[GG * 5];
    __shared__ int   lloc[256];
    __shared__ int   lcnt;
    __shared__ float red1[4];

    int b = blockIdx.y;
    int tid = threadIdx.x, w = tid >> 6, ln = tid & 63;
    float* acc = (float*)ctrl;
    int*   cnt = ctrl + 8;

    // cheap poison->0 init: this block's words + block(0,0) covers the rest
    if (tid == 0) atomicCAS((unsigned*)&cnt[b], POISON, 0u);
    if (tid == 1) atomicCAS((unsigned*)&ctrl[2], POISON, 0u);
    if (blockIdx.x == 0 && b == 0 && tid < 48) atomicCAS((unsigned*)&ctrl[tid], POISON, 0u);
    if (tid == 0) lcnt = 0;

    int nb  = gridDim.x * gridDim.y;
    int bid = b * gridDim.x + blockIdx.x;
    for (int i = bid * 256 + tid; i < BB * AA; i += nb * 256) matchcnt[i] = 0;

    for (int i = tid; i < GG * 5; i += 256) lgt[i] = labels[b * GG * 5 + i];
    __syncthreads();

    // ---- fg flag + wave compaction ----
    int a = blockIdx.x * 256 + tid;
    bool fg = false;
    if (a < AA) {
        float stv = st_[a];
        float xc = __fmul_rn(__fadd_rn(xs_[a], 0.5f), stv);
        float yc = __fmul_rn(__fadd_rn(ys_[a], 0.5f), stv);
        float r  = __fmul_rn(1.5f, stv);
        for (int g = 0; g < GG && !fg; g++)
            fg = dev_in(lgt[g * 5 + 1], lgt[g * 5 + 2], xc, yc, r);
    }
    ull mk = __ballot(fg);
    int cw = __popcll(mk);
    int wbase = 0;
    if (ln == 0 && cw) wbase = atomicAdd(&lcnt, cw);
    wbase = __shfl(wbase, 0, 64);
    if (fg) lloc[wbase + __popcll(mk & ((1ull << ln) - 1ull))] = a;

    // ---- coalesced obj softplus scan over the whole outputs array ----
    float sp = 0.0f;
    const float4* o4 = (const float4*)outputs;
    for (int i = bid * 256 + tid; i < NF4; i += nb * 256) {
        float4 v = o4[i];
        unsigned r = (unsigned)(i * 4) % 85u;
        if (r == 4u)      sp += softplus_bce(v.x);
        else if (r == 3u) sp += softplus_bce(v.y);
        else if (r == 2u) sp += softplus_bce(v.z);
        else if (r == 1u) sp += softplus_bce(v.w);
    }
    sp = wave_sum(sp);
    if (ln == 0) red1[w] = sp;
    __syncthreads();

    if (tid == 0) {
        atomicAdd(&acc[2], red1[0] + red1[1] + red1[2] + red1[3]);
        int base = atomicAdd(&cnt[b], lcnt);
        lloc[255] = base;          // reuse tail slot to broadcast (lcnt <= 256 incl. it? no:
    }                              // lcnt<=256 and lloc[255] only valid if lcnt<256; see below
    __syncthreads();
    // NOTE: lcnt can be 256 (all anchors fg) only if a whole 256-window is inside centers —
    // geometrically impossible here (max ~27 cells/gt*40 spread); but guard anyway:
    int m = lcnt;
    int base = lloc[255];
    for (int j = tid; j < m && j < 255; j += 256)
        if (base + j < CAP) alist[b * CAP + base + j] = lloc[j];
}

// ---------- K1b: fg anchors — balanced chunks, wave-staged rows, class terms ----------
__global__ __launch_bounds__(256) void k1b_cls(
    const float* __restrict__ outputs, const float* __restrict__ labels,
    const float* __restrict__ xs_, const float* __restrict__ ys_, const float* __restrict__ st_,
    const int* __restrict__ ctrl, const int* __restrict__ alist,
    float4* __restrict__ blist, float4* __restrict__ glist,
    float2* __restrict__ misc, float* __restrict__ clsterm)
{
    int b = blockIdx.y;
    int i0 = blockIdx.x * 64;
    int n = ctrl[8 + b]; n = n > CAP ? CAP : n;
    if (i0 >= n) return;                      // block-uniform — safe before barriers

    __shared__ float rows[64 * NO];           // 21.8 KB
    __shared__ float lgt[GG * 5];
    __shared__ int   arow[64];
    __shared__ float2 red2[4][64];

    int tid = threadIdx.x;
    int w = tid >> 6, ln = tid & 63;
    for (int t = tid; t < GG * 5; t += 256) lgt[t] = labels[b * GG * 5 + t];

    for (int rr = 0; rr < 16; rr++) {
        int row = i0 + w * 16 + rr;
        if (row < n) {
            int a = alist[b * CAP + row];
            const float* src = outputs + ((size_t)b * AA + a) * NO;
            int rl = w * 16 + rr;
            rows[rl * NO + ln] = src[ln];
            if (ln < NO - 64) rows[rl * NO + 64 + ln] = src[64 + ln];
            if (ln == 0) arow[rl] = a;
        }
    }
    __syncthreads();

    int il = ln;
    int i = i0 + il;
    bool valid = i < n;
    const float* R = rows + il * NO;
    float obj = R[4];

    float s1 = 0.0f, s2 = 0.0f;
    if (valid) {
        int c0 = w * 20;
#pragma unroll 4
        for (int j = 0; j < 20; j++) {
            float x = R[5 + c0 + j];
            float m = __fmul_rn(x, obj);
            float p = __fsqrt_rn(m);
            s1 += __logf(__fsub_rn(1.0f, p));                          // log1p(-p)
            s2 += softplus_bce(x);                                     // cls BCE base
        }
    }
    red2[w][il] = make_float2(s1, s2);
    __syncthreads();

    if (!valid) return;
    float s1t = red2[0][il].x + red2[1][il].x + red2[2][il].x + red2[3][il].x;
    float s2t = red2[0][il].y + red2[1][il].y + red2[2][il].y + red2[3][il].y;
    float nsl = -s1t;

    if (w == 0) {
        int a = arow[il];
        float stv = st_[a];
        float xc = __fmul_rn(__fadd_rn(xs_[a], 0.5f), stv);
        float yc = __fmul_rn(__fadd_rn(ys_[a], 0.5f), stv);
        float r  = __fmul_rn(1.5f, stv);
        blist[b * CAP + i] = make_float4(R[0], R[1], R[2], R[3]);
        glist[b * CAP + i] = make_float4(xc, yc, r, stv);
        misc[b * CAP + i]  = make_float2(s2t, obj);
    }
#pragma unroll
    for (int gi = 0; gi < 10; gi++) {
        int g = w * 10 + gi;
        int gc = (int)lgt[g * 5];
        float m = __fmul_rn(R[5 + gc], obj);
        float p = __fsqrt_rn(m);
        float term = __fsub_rn(__fmul_rn(0.5f, __logf(m)), __logf(__fsub_rn(1.0f, p)));
        clsterm[((size_t)b * GG + g) * CAP + i] = __fsub_rn(nsl, term);   // coalesced in i
    }
}

// ---------- K2: 4 independent (b,g) waves per block — register-only top-10s ----------
__global__ __launch_bounds__(256) void k2_assign(
    const float* __restrict__ labels,
    int* __restrict__ ctrl,
    const int* __restrict__ alist,
    const float4* __restrict__ blist, const float4* __restrict__ glist,
    const float* __restrict__ clsterm,
    int* __restrict__ matchcnt, int2* __restrict__ wl)
{
    int w = threadIdx.x >> 6, ln = threadIdx.x & 63;
    int pair = blockIdx.x * 4 + w;        // < BB*GG = 1280
    int b = pair / GG, g = pair - b * GG;
    int* cnt   = ctrl + 8;
    int* wlcnt = ctrl + 40;

    const float* L = labels + (b * GG + g) * 5;
    float gx = L[1], gy = L[2], gw = L[3], gh = L[4];
    int n = cnt[b]; n = n > CAP ? CAP : n;

    const float*  ctp = clsterm + ((size_t)b * GG + g) * CAP;
    const float4* bp  = blist + b * CAP;
    const float4* gp  = glist + b * CAP;
    const int*    ap  = alist + b * CAP;

    ull t[10]; float tv[10];
#pragma unroll
    for (int k = 0; k < 10; k++) { t[k] = U64MAX; tv[k] = 0.0f; }

    for (int i = ln; i < n; i += 64) {
        float4 pb = bp[i];
        float4 gm = gp[i];
        float2 ci = cost_iou(gx, gy, gw, gh, pb.x, pb.y, pb.z, pb.w,
                             gm.x, gm.y, gm.z, ctp[i], 1.0f);
        unsigned u = __float_as_uint(ci.x);
        u ^= (u & 0x80000000u) ? 0xFFFFFFFFu : 0x80000000u;
        ull key = ((ull)u << 32) | (unsigned)((ap[i] << 11) | i);
        if (key < t[9]) {
            int p = 0;
#pragma unroll
            for (int k = 0; k < 10; k++) p += (t[k] < key) ? 1 : 0;
#pragma unroll
            for (int k = 9; k >= 1; k--) t[k] = (k > p) ? t[k - 1] : t[k];
#pragma unroll
            for (int k = 0; k < 10; k++) if (k == p) t[k] = key;
        }
        float v = ci.y;
        if (v > tv[9]) {
            int p = 0;
#pragma unroll
            for (int k = 0; k < 10; k++) p += (tv[k] > v) ? 1 : 0;
#pragma unroll
            for (int k = 9; k >= 1; k--) tv[k] = (k > p) ? tv[k - 1] : tv[k];
#pragma unroll
            for (int k = 0; k < 10; k++) if (k == p) tv[k] = v;
        }
    }

    ull mykey = U64MAX;
#pragma unroll
    for (int r = 0; r < 10; r++) {
        ull mn = wave_min_u64(t[0]);
        if (ln == r) mykey = mn;
        bool own = (t[0] == mn);
#pragma unroll
        for (int k = 0; k < 9; k++) t[k] = own ? t[k + 1] : t[k];
        t[9] = own ? U64MAX : t[9];
    }
    float isum = 0.0f;
#pragma unroll
    for (int r = 0; r < 10; r++) {
        float mv = wave_max_f(tv[0]);
        isum += mv;
        ull bal = __ballot(tv[0] == mv);
        int first = (int)__ffsll((long long)bal) - 1;
        bool own = (ln == first);
#pragma unroll
        for (int k = 0; k < 9; k++) tv[k] = own ? tv[k + 1] : tv[k];
        tv[9] = own ? 0.0f : tv[9];
    }

    int dk = (int)isum;
    dk = dk < 1 ? 1 : (dk > 10 ? 10 : dk);
    if (ln < dk && mykey != U64MAX) {
        unsigned low = (unsigned)mykey;
        int a = (int)(low >> 11);
        int i2 = (int)(low & 2047);
        int idx = b * AA + a;
        if (atomicAdd(&matchcnt[idx], 1) == 0) {
            int wp = atomicAdd(wlcnt, 1);
            if (wp < CAPW) wl[wp] = make_int2(idx, (g << 16) | i2);
        }
    }
}

// ---------- K4: dense loss over matched worklist + ticket finalize ----------
__global__ __launch_bounds__(256) void k4_loss(
    const float* __restrict__ outputs, const float* __restrict__ origin,
    const float* __restrict__ labels,
    const float* __restrict__ xs_, const float* __restrict__ ys_, const float* __restrict__ st_,
    const float4* __restrict__ blist, const float4* __restrict__ glist,
    const float2* __restrict__ misc, const float* __restrict__ clsterm,
    const int* __restrict__ matchcnt,
    const int2* __restrict__ wl, int* __restrict__ ctrl,
    float* __restrict__ out)
{
    float* acc = (float*)ctrl;
    int* wlcnt = ctrl + 40;
    int* fin   = ctrl + 41;

    int t = blockIdx.x * 256 + threadIdx.x;
    int nw = *wlcnt; nw = nw > CAPW ? CAPW : nw;

    float t_fg = 0.0f, t_iou = 0.0f, t_obj = 0.0f, t_cls = 0.0f, t_l1 = 0.0f;
    if (t < nw) {
        int2 e = wl[t];
        int idx = e.x;
        int b = idx / AA;
        int a = idx - b * AA;
        int ci = e.y & 0xFFFF;
        int g1 = e.y >> 16;
        int mcnt = matchcnt[idx];

        float4 pb = blist[b * CAP + ci];
        float4 gm = glist[b * CAP + ci];
        float2 mo = misc[b * CAP + ci];   // (sbce, obj)
        const float* Lb = labels + b * GG * 5;

        int mg;
        if (mcnt == 1) {
            mg = g1;
        } else {
            mg = 0; float best = FLT_MAX;
            for (int g = 0; g < GG; g++) {
                float ct = clsterm[((size_t)b * GG + g) * CAP + ci];
                float2 r = cost_iou(Lb[g * 5 + 1], Lb[g * 5 + 2], Lb[g * 5 + 3], Lb[g * 5 + 4],
                                    pb.x, pb.y, pb.z, pb.w, gm.x, gm.y, gm.z, ct, 1.0f);
                if (r.x < best) { best = r.x; mg = g; }
            }
        }
        t_fg = 1.0f;
        t_obj = -mo.y;   // BCE(x,1)-BCE(x,0); base summed in K1a
        float gx = Lb[mg * 5 + 1], gy = Lb[mg * 5 + 2], gw = Lb[mg * 5 + 3], gh = Lb[mg * 5 + 4];
        int mcls = (int)Lb[mg * 5];
        float ctm = clsterm[((size_t)b * GG + mg) * CAP + ci];
        float2 r = cost_iou(gx, gy, gw, gh, pb.x, pb.y, pb.z, pb.w, gm.x, gm.y, gm.z, ctm, 1.0f);
        float pred_iou = r.y;
        float tlx = fmaxf(pb.x - pb.z * 0.5f, gx - gw * 0.5f);
        float tly = fmaxf(pb.y - pb.w * 0.5f, gy - gh * 0.5f);
        float brx = fminf(pb.x + pb.z * 0.5f, gx + gw * 0.5f);
        float bry = fminf(pb.y + pb.w * 0.5f, gy + gh * 0.5f);
        float en = (tlx < brx && tly < bry) ? 1.0f : 0.0f;
        float ai = (brx - tlx) * (bry - tly) * en;
        float iou = ai / (pb.z * pb.w + gw * gh - ai + 1e-16f);
        t_iou = 1.0f - iou * iou;
        const float* op = origin + (size_t)idx * 4;
        float stv = st_[a], xsv = xs_[a], ysv = ys_[a];
        t_l1 = fabsf(op[0] - (gx / stv - xsv)) + fabsf(op[1] - (gy / stv - ysv))
             + fabsf(op[2] - logf(gw / stv + 1e-8f)) + fabsf(op[3] - logf(gh / stv + 1e-8f));
        t_cls = mo.x - outputs[(size_t)idx * NO + 5 + mcls] * pred_iou;
    }

    t_fg = wave_sum(t_fg); t_iou = wave_sum(t_iou); t_obj = wave_sum(t_obj);
    t_cls = wave_sum(t_cls); t_l1 = wave_sum(t_l1);
    __shared__ float red[5][4];
    int wv = threadIdx.x >> 6, ln = threadIdx.x & 63;
    if (ln == 0) { red[0][wv] = t_fg; red[1][wv] = t_iou; red[2][wv] = t_obj; red[3][wv] = t_cls; red[4][wv] = t_l1; }
    __syncthreads();
    if (threadIdx.x == 0) {
        atomicAdd(&acc[0], red[0][0] + red[0][1] + red[0][2] + red[0][3]);
        atomicAdd(&acc[1], red[1][0] + red[1][1] + red[1][2] + red[1][3]);
        atomicAdd(&acc[2], red[2][0] + red[2][1] + red[2][2] + red[2][3]);
        atomicAdd(&acc[3], red[3][0] + red[3][1] + red[3][2] + red[3][3]);
        atomicAdd(&acc[4], red[4][0] + red[4][1] + red[4][2] + red[4][3]);
        __threadfence();
        int tkt = atomicAdd(fin, 1);
        if (tkt == (int)gridDim.x - 1) {
            float a0 = atomicAdd(&acc[0], 0.0f);
            float a1 = atomicAdd(&acc[1], 0.0f);
            float a2 = atomicAdd(&acc[2], 0.0f);
            float a3 = atomicAdd(&acc[3], 0.0f);
            float a4 = atomicAdd(&acc[4], 0.0f);
            float nfg = fmaxf(a0, 1.0f);
            float li = 5.0f * a1 / nfg;
            float lo = a2 / nfg;
            float lc = a3 / nfg;
            float ll = a4 / nfg;
            out[0] = li + lo + lc + ll;
            out[1] = li;
            out[2] = lo;
            out[3] = lc;
            out[4] = ll;
            out[5] = nfg / (float)(BB * GG);
        }
    }
}

// ---------- workspace layout (16B-aligned blocks) ----------
static constexpr size_t NBA       = (size_t)BB * AA;                 // 268800
static constexpr size_t OFF_MC    = 256;                             // ctrl first (256 B)
static constexpr size_t OFF_ALIST = OFF_MC + NBA * 4;
static constexpr size_t OFF_BL    = OFF_ALIST + (size_t)BB * CAP * 4;
static constexpr size_t OFF_GL    = OFF_BL + (size_t)BB * CAP * 16;
static constexpr size_t OFF_MISC  = OFF_GL + (size_t)BB * CAP * 16;
static constexpr size_t OFF_CT    = OFF_MISC + (size_t)BB * CAP * 8;
static constexpr size_t OFF_WL    = OFF_CT + (size_t)BB * GG * CAP * 4;
// total = OFF_WL + CAPW*8 ≈ 15 MB

extern "C" void kernel_launch(void* const* d_in, const int* in_sizes, int n_in,
                              void* d_out, int out_size, void* d_ws, size_t ws_size,
                              hipStream_t stream)
{
    (void)in_sizes; (void)n_in; (void)out_size; (void)ws_size;
    const float* outputs = (const float*)d_in[0];
    const float* origin  = (const float*)d_in[1];
    const float* labels  = (const float*)d_in[2];
    const float* xs_     = (const float*)d_in[3];
    const float* ys_     = (const float*)d_in[4];
    const float* st_     = (const float*)d_in[5];
    float* out = (float*)d_out;
    char* ws = (char*)d_ws;

    int*    ctrl     = (int*)(ws);
    int*    matchcnt = (int*)(ws + OFF_MC);
    int*    alist    = (int*)(ws + OFF_ALIST);
    float4* blist    = (float4*)(ws + OFF_BL);
    float4* glist    = (float4*)(ws + OFF_GL);
    float2* misc     = (float2*)(ws + OFF_MISC);
    float*  clsterm  = (float*)(ws + OFF_CT);
    int2*   wl       = (int2*)(ws + OFF_WL);

    dim3 grid1((AA + 255) / 256, BB);   // 33 x 32
    k1a_fg<<<grid1, 256, 0, stream>>>(outputs, labels, xs_, ys_, st_, ctrl, matchcnt, alist);

    dim3 grid1b(CAP / 64, BB);          // 32 x 32, blocks beyond n exit immediately
    k1b_cls<<<grid1b, 256, 0, stream>>>(outputs, labels, xs_, ys_, st_, ctrl, alist,
                                        blist, glist, misc, clsterm);

    k2_assign<<<BB * GG / 4, 256, 0, stream>>>(labels, ctrl, alist, blist, glist, clsterm,
                                               matchcnt, wl);

    k4_loss<<<CAPW / 256, 256, 0, stream>>>(outputs, origin, labels, xs_, ys_, st_,
                                            blist, glist, misc, clsterm, matchcnt, wl,
                                            ctrl, out);
}

// Round 9
// 237.816 us; speedup vs baseline: 1.1520x; 1.1520x over previous
//
#include <hip/hip_runtime.h>
#include <cfloat>

#define BB 32
#define AA 8400
#define GG 40
#define NC 80
#define NO 85
#define CAP 2048    // >= geometric bound ~27 anchors/gt * 40 gts = 1080
#define CAPW 13312  // >= 1280 gts * dk_max 10 = 12800
#define POISON 0xAAAAAAAAu
#define K4GRID 104  // 2x worklist coverage; extra blocks feed the obj gather

typedef unsigned long long ull;
#define U64MAX 0xFFFFFFFFFFFFFFFFull

// ---------- deterministic helpers: explicit _rn ops (no FMA contraction) so every
// call site produces bitwise-identical values ----------

__device__ inline bool dev_in(float gx, float gy, float xc, float yc, float r)
{
    float dl = __fsub_rn(xc, __fsub_rn(gx, r));
    float dr = __fsub_rn(__fadd_rn(gx, r), xc);
    float dt = __fsub_rn(yc, __fsub_rn(gy, r));
    float db = __fsub_rn(__fadd_rn(gy, r), yc);
    return fminf(fminf(dl, dr), fminf(dt, db)) > 0.0f;
}

__device__ inline float2 cost_iou(float gx, float gy, float gw, float gh,
                                  float px, float py, float pw, float ph,
                                  float xc, float yc, float r,
                                  float ct, float fg)
{
    bool in = dev_in(gx, gy, xc, yc, r);
    float gw2 = __fmul_rn(gw, 0.5f), gh2 = __fmul_rn(gh, 0.5f);
    float pw2 = __fmul_rn(pw, 0.5f), ph2 = __fmul_rn(ph, 0.5f);
    float tlx = fmaxf(__fsub_rn(gx, gw2), __fsub_rn(px, pw2));
    float tly = fmaxf(__fsub_rn(gy, gh2), __fsub_rn(py, ph2));
    float brx = fminf(__fadd_rn(gx, gw2), __fadd_rn(px, pw2));
    float bry = fminf(__fadd_rn(gy, gh2), __fadd_rn(py, ph2));
    float en = (tlx < brx && tly < bry) ? 1.0f : 0.0f;
    float ai = __fmul_rn(__fmul_rn(__fsub_rn(brx, tlx), __fsub_rn(bry, tly)), en);
    float ag = __fmul_rn(gw, gh);
    float ap = __fmul_rn(pw, ph);
    float iou = ai / __fsub_rn(__fadd_rn(ag, ap), ai);
    iou = (fg != 0.0f) ? iou : 0.0f;
    float icost = -__logf(__fadd_rn(iou, 1e-8f));
    float cost = __fadd_rn(__fadd_rn(ct, __fmul_rn(3.0f, icost)), in ? 0.0f : 1000000.0f);
    cost = (fg != 0.0f) ? cost : 1000000000.0f;
    return make_float2(cost, iou);
}

__device__ inline float softplus_bce(float x)
{
    return fmaxf(x, 0.0f) + __logf(1.0f + __expf(-fabsf(x)));
}

__device__ inline float wave_sum(float v)
{
#pragma unroll
    for (int o = 32; o > 0; o >>= 1) v += __shfl_down(v, o, 64);
    return v;
}

__device__ inline ull wave_min_u64(ull v)
{
#pragma unroll
    for (int o = 1; o < 64; o <<= 1) {
        ull w = (ull)__shfl_xor((long long)v, o, 64);
        v = w < v ? w : v;
    }
    return v;
}

__device__ inline float wave_max_f(float v)
{
#pragma unroll
    for (int o = 1; o < 64; o <<= 1) v = fmaxf(v, __shfl_xor(v, o, 64));
    return v;
}

// ctrl layout (ints): [0..7]=acc(float), [8..39]=cnt[32], [40]=wlcnt, [41]=fin

// ---------- K1a: ctrl init + matchcnt zero + fg compaction (no heavy memory work) ----
__global__ __launch_bounds__(256) void k1a_fg(
    const float* __restrict__ labels,
    const float* __restrict__ xs_, const float* __restrict__ ys_, const float* __restrict__ st_,
    int* __restrict__ ctrl, int* __restrict__ matchcnt, int* __restrict__ alist)
{
    __shared__ float lgt[GG * 5];
    __shared__ int   lloc[256];
    __shared__ int   lcnt, sbase;

    int b = blockIdx.y;
    int tid = threadIdx.x, ln = tid & 63;
    int* cnt = ctrl + 8;

    // poison->0 init: 1 CAS/block on this image's counter; block(0,0) covers all 48 words
    if (tid == 0) atomicCAS((unsigned*)&cnt[b], POISON, 0u);
    if (blockIdx.x == 0 && b == 0 && tid < 48) atomicCAS((unsigned*)&ctrl[tid], POISON, 0u);
    if (tid == 0) lcnt = 0;

    int nb  = gridDim.x * gridDim.y;
    int bid = b * gridDim.x + blockIdx.x;
    for (int i = bid * 256 + tid; i < BB * AA; i += nb * 256) matchcnt[i] = 0;

    for (int i = tid; i < GG * 5; i += 256) lgt[i] = labels[b * GG * 5 + i];
    __syncthreads();

    int a = blockIdx.x * 256 + tid;
    bool fg = false;
    if (a < AA) {
        float stv = st_[a];
        float xc = __fmul_rn(__fadd_rn(xs_[a], 0.5f), stv);
        float yc = __fmul_rn(__fadd_rn(ys_[a], 0.5f), stv);
        float r  = __fmul_rn(1.5f, stv);
        for (int g = 0; g < GG && !fg; g++)
            fg = dev_in(lgt[g * 5 + 1], lgt[g * 5 + 2], xc, yc, r);
    }
    ull mk = __ballot(fg);
    int cw = __popcll(mk);
    int wbase = 0;
    if (ln == 0 && cw) wbase = atomicAdd(&lcnt, cw);
    wbase = __shfl(wbase, 0, 64);
    if (fg) lloc[wbase + __popcll(mk & ((1ull << ln) - 1ull))] = a;
    __syncthreads();
    if (tid == 0) sbase = atomicAdd(&cnt[b], lcnt);
    __syncthreads();
    int m = lcnt, base = sbase;
    for (int j = tid; j < m; j += 256)
        if (base + j < CAP) alist[b * CAP + base + j] = lloc[j];
}

// ---------- K1b: fg anchors — balanced chunks, wave-staged rows, class terms ----------
__global__ __launch_bounds__(256) void k1b_cls(
    const float* __restrict__ outputs, const float* __restrict__ labels,
    const float* __restrict__ xs_, const float* __restrict__ ys_, const float* __restrict__ st_,
    const int* __restrict__ ctrl, const int* __restrict__ alist,
    float4* __restrict__ blist, float4* __restrict__ glist,
    float2* __restrict__ misc, float* __restrict__ clsterm)
{
    int b = blockIdx.y;
    int i0 = blockIdx.x * 64;
    int n = ctrl[8 + b]; n = n > CAP ? CAP : n;
    if (i0 >= n) return;                      // block-uniform — safe before barriers

    __shared__ float rows[64 * NO];           // 21.8 KB
    __shared__ float lgt[GG * 5];
    __shared__ int   arow[64];
    __shared__ float2 red2[4][64];

    int tid = threadIdx.x;
    int w = tid >> 6, ln = tid & 63;
    for (int t = tid; t < GG * 5; t += 256) lgt[t] = labels[b * GG * 5 + t];

    for (int rr = 0; rr < 16; rr++) {
        int row = i0 + w * 16 + rr;
        if (row < n) {
            int a = alist[b * CAP + row];
            const float* src = outputs + ((size_t)b * AA + a) * NO;
            int rl = w * 16 + rr;
            rows[rl * NO + ln] = src[ln];
            if (ln < NO - 64) rows[rl * NO + 64 + ln] = src[64 + ln];
            if (ln == 0) arow[rl] = a;
        }
    }
    __syncthreads();

    int il = ln;
    int i = i0 + il;
    bool valid = i < n;
    const float* R = rows + il * NO;
    float obj = R[4];

    float s1 = 0.0f, s2 = 0.0f;
    if (valid) {
        int c0 = w * 20;
#pragma unroll 4
        for (int j = 0; j < 20; j++) {
            float x = R[5 + c0 + j];
            float m = __fmul_rn(x, obj);
            float p = __fsqrt_rn(m);
            s1 += __logf(__fsub_rn(1.0f, p));                          // log1p(-p)
            s2 += softplus_bce(x);                                     // cls BCE base
        }
    }
    red2[w][il] = make_float2(s1, s2);
    __syncthreads();

    if (!valid) return;
    float s1t = red2[0][il].x + red2[1][il].x + red2[2][il].x + red2[3][il].x;
    float s2t = red2[0][il].y + red2[1][il].y + red2[2][il].y + red2[3][il].y;
    float nsl = -s1t;

    if (w == 0) {
        int a = arow[il];
        float stv = st_[a];
        float xc = __fmul_rn(__fadd_rn(xs_[a], 0.5f), stv);
        float yc = __fmul_rn(__fadd_rn(ys_[a], 0.5f), stv);
        float r  = __fmul_rn(1.5f, stv);
        blist[b * CAP + i] = make_float4(R[0], R[1], R[2], R[3]);
        glist[b * CAP + i] = make_float4(xc, yc, r, stv);
        misc[b * CAP + i]  = make_float2(s2t, obj);
    }
#pragma unroll
    for (int gi = 0; gi < 10; gi++) {
        int g = w * 10 + gi;
        int gc = (int)lgt[g * 5];
        float m = __fmul_rn(R[5 + gc], obj);
        float p = __fsqrt_rn(m);
        float term = __fsub_rn(__fmul_rn(0.5f, __logf(m)), __logf(__fsub_rn(1.0f, p)));
        clsterm[((size_t)b * GG + g) * CAP + i] = __fsub_rn(nsl, term);   // coalesced in i
    }
}

// ---------- K2: 4 independent (b,g) waves per block — register-only top-10s ----------
__global__ __launch_bounds__(256) void k2_assign(
    const float* __restrict__ labels,
    int* __restrict__ ctrl,
    const int* __restrict__ alist,
    const float4* __restrict__ blist, const float4* __restrict__ glist,
    const float* __restrict__ clsterm,
    int* __restrict__ matchcnt, int2* __restrict__ wl)
{
    int w = threadIdx.x >> 6, ln = threadIdx.x & 63;
    int pair = blockIdx.x * 4 + w;        // < BB*GG = 1280
    int b = pair / GG, g = pair - b * GG;
    int* cnt   = ctrl + 8;
    int* wlcnt = ctrl + 40;

    const float* L = labels + (b * GG + g) * 5;
    float gx = L[1], gy = L[2], gw = L[3], gh = L[4];
    int n = cnt[b]; n = n > CAP ? CAP : n;

    const float*  ctp = clsterm + ((size_t)b * GG + g) * CAP;
    const float4* bp  = blist + b * CAP;
    const float4* gp  = glist + b * CAP;
    const int*    ap  = alist + b * CAP;

    ull t[10]; float tv[10];
#pragma unroll
    for (int k = 0; k < 10; k++) { t[k] = U64MAX; tv[k] = 0.0f; }

    for (int i = ln; i < n; i += 64) {
        float4 pb = bp[i];
        float4 gm = gp[i];
        float2 ci = cost_iou(gx, gy, gw, gh, pb.x, pb.y, pb.z, pb.w,
                             gm.x, gm.y, gm.z, ctp[i], 1.0f);
        unsigned u = __float_as_uint(ci.x);
        u ^= (u & 0x80000000u) ? 0xFFFFFFFFu : 0x80000000u;
        ull key = ((ull)u << 32) | (unsigned)((ap[i] << 11) | i);
        if (key < t[9]) {
            int p = 0;
#pragma unroll
            for (int k = 0; k < 10; k++) p += (t[k] < key) ? 1 : 0;
#pragma unroll
            for (int k = 9; k >= 1; k--) t[k] = (k > p) ? t[k - 1] : t[k];
#pragma unroll
            for (int k = 0; k < 10; k++) if (k == p) t[k] = key;
        }
        float v = ci.y;
        if (v > tv[9]) {
            int p = 0;
#pragma unroll
            for (int k = 0; k < 10; k++) p += (tv[k] > v) ? 1 : 0;
#pragma unroll
            for (int k = 9; k >= 1; k--) tv[k] = (k > p) ? tv[k - 1] : tv[k];
#pragma unroll
            for (int k = 0; k < 10; k++) if (k == p) tv[k] = v;
        }
    }

    ull mykey = U64MAX;
#pragma unroll
    for (int r = 0; r < 10; r++) {
        ull mn = wave_min_u64(t[0]);
        if (ln == r) mykey = mn;
        bool own = (t[0] == mn);
#pragma unroll
        for (int k = 0; k < 9; k++) t[k] = own ? t[k + 1] : t[k];
        t[9] = own ? U64MAX : t[9];
    }
    float isum = 0.0f;
#pragma unroll
    for (int r = 0; r < 10; r++) {
        float mv = wave_max_f(tv[0]);
        isum += mv;
        ull bal = __ballot(tv[0] == mv);
        int first = (int)__ffsll((long long)bal) - 1;
        bool own = (ln == first);
#pragma unroll
        for (int k = 0; k < 9; k++) tv[k] = own ? tv[k + 1] : tv[k];
        tv[9] = own ? 0.0f : tv[9];
    }

    int dk = (int)isum;
    dk = dk < 1 ? 1 : (dk > 10 ? 10 : dk);
    if (ln < dk && mykey != U64MAX) {
        unsigned low = (unsigned)mykey;
        int a = (int)(low >> 11);
        int i2 = (int)(low & 2047);
        int idx = b * AA + a;
        if (atomicAdd(&matchcnt[idx], 1) == 0) {
            int wp = atomicAdd(wlcnt, 1);
            if (wp < CAPW) wl[wp] = make_int2(idx, (g << 16) | i2);
        }
    }
}

// ---------- K4: worklist loss + grid-stride all-anchor obj-BCE + ticket finalize ------
__global__ __launch_bounds__(256) void k4_loss(
    const float* __restrict__ outputs, const float* __restrict__ origin,
    const float* __restrict__ labels,
    const float* __restrict__ xs_, const float* __restrict__ ys_, const float* __restrict__ st_,
    const float4* __restrict__ blist, const float4* __restrict__ glist,
    const float2* __restrict__ misc, const float* __restrict__ clsterm,
    const int* __restrict__ matchcnt,
    const int2* __restrict__ wl, int* __restrict__ ctrl,
    float* __restrict__ out)
{
    float* acc = (float*)ctrl;
    int* wlcnt = ctrl + 40;
    int* fin   = ctrl + 41;

    int tid = threadIdx.x;
    int gid = blockIdx.x * 256 + tid;
    int nw = *wlcnt; nw = nw > CAPW ? CAPW : nw;

    float t_fg = 0.0f, t_iou = 0.0f, t_obj = 0.0f, t_cls = 0.0f, t_l1 = 0.0f;

    // all-anchor objectness BCE base (gather; ~10 independent loads/thread for ILP)
    for (int i = gid; i < BB * AA; i += K4GRID * 256)
        t_obj += softplus_bce(outputs[(size_t)i * NO + 4]);

    if (gid < nw) {
        int2 e = wl[gid];
        int idx = e.x;
        int b = idx / AA;
        int a = idx - b * AA;
        int ci = e.y & 0xFFFF;
        int g1 = e.y >> 16;
        int mcnt = matchcnt[idx];

        float4 pb = blist[b * CAP + ci];
        float4 gm = glist[b * CAP + ci];
        float2 mo = misc[b * CAP + ci];   // (sbce, obj)
        const float* Lb = labels + b * GG * 5;

        int mg;
        if (mcnt == 1) {
            mg = g1;
        } else {
            mg = 0; float best = FLT_MAX;
            for (int g = 0; g < GG; g++) {
                float ct = clsterm[((size_t)b * GG + g) * CAP + ci];
                float2 r = cost_iou(Lb[g * 5 + 1], Lb[g * 5 + 2], Lb[g * 5 + 3], Lb[g * 5 + 4],
                                    pb.x, pb.y, pb.z, pb.w, gm.x, gm.y, gm.z, ct, 1.0f);
                if (r.x < best) { best = r.x; mg = g; }
            }
        }
        t_fg = 1.0f;
        t_obj += -mo.y;   // BCE(x,1)-BCE(x,0)
        float gx = Lb[mg * 5 + 1], gy = Lb[mg * 5 + 2], gw = Lb[mg * 5 + 3], gh = Lb[mg * 5 + 4];
        int mcls = (int)Lb[mg * 5];
        float ctm = clsterm[((size_t)b * GG + mg) * CAP + ci];
        float2 r = cost_iou(gx, gy, gw, gh, pb.x, pb.y, pb.z, pb.w, gm.x, gm.y, gm.z, ctm, 1.0f);
        float pred_iou = r.y;
        float tlx = fmaxf(pb.x - pb.z * 0.5f, gx - gw * 0.5f);
        float tly = fmaxf(pb.y - pb.w * 0.5f, gy - gh * 0.5f);
        float brx = fminf(pb.x + pb.z * 0.5f, gx + gw * 0.5f);
        float bry = fminf(pb.y + pb.w * 0.5f, gy + gh * 0.5f);
        float en = (tlx < brx && tly < bry) ? 1.0f : 0.0f;
        float ai = (brx - tlx) * (bry - tly) * en;
        float iou = ai / (pb.z * pb.w + gw * gh - ai + 1e-16f);
        t_iou = 1.0f - iou * iou;
        const float* op = origin + (size_t)idx * 4;
        float stv = st_[a], xsv = xs_[a], ysv = ys_[a];
        t_l1 = fabsf(op[0] - (gx / stv - xsv)) + fabsf(op[1] - (gy / stv - ysv))
             + fabsf(op[2] - logf(gw / stv + 1e-8f)) + fabsf(op[3] - logf(gh / stv + 1e-8f));
        t_cls = mo.x - outputs[(size_t)idx * NO + 5 + mcls] * pred_iou;
    }

    t_fg = wave_sum(t_fg); t_iou = wave_sum(t_iou); t_obj = wave_sum(t_obj);
    t_cls = wave_sum(t_cls); t_l1 = wave_sum(t_l1);
    __shared__ float red[5][4];
    int wv = threadIdx.x >> 6, ln = threadIdx.x & 63;
    if (ln == 0) { red[0][wv] = t_fg; red[1][wv] = t_iou; red[2][wv] = t_obj; red[3][wv] = t_cls; red[4][wv] = t_l1; }
    __syncthreads();
    if (threadIdx.x == 0) {
        atomicAdd(&acc[0], red[0][0] + red[0][1] + red[0][2] + red[0][3]);
        atomicAdd(&acc[1], red[1][0] + red[1][1] + red[1][2] + red[1][3]);
        atomicAdd(&acc[2], red[2][0] + red[2][1] + red[2][2] + red[2][3]);
        atomicAdd(&acc[3], red[3][0] + red[3][1] + red[3][2] + red[3][3]);
        atomicAdd(&acc[4], red[4][0] + red[4][1] + red[4][2] + red[4][3]);
        __threadfence();
        int tkt = atomicAdd(fin, 1);
        if (tkt == (int)gridDim.x - 1) {
            float a0 = atomicAdd(&acc[0], 0.0f);
            float a1 = atomicAdd(&acc[1], 0.0f);
            float a2 = atomicAdd(&acc[2], 0.0f);
            float a3 = atomicAdd(&acc[3], 0.0f);
            float a4 = atomicAdd(&acc[4], 0.0f);
            float nfg = fmaxf(a0, 1.0f);
            float li = 5.0f * a1 / nfg;
            float lo = a2 / nfg;
            float lc = a3 / nfg;
            float ll = a4 / nfg;
            out[0] = li + lo + lc + ll;
            out[1] = li;
            out[2] = lo;
            out[3] = lc;
            out[4] = ll;
            out[5] = nfg / (float)(BB * GG);
        }
    }
}

// ---------- workspace layout (16B-aligned blocks) ----------
static constexpr size_t NBA       = (size_t)BB * AA;                 // 268800
static constexpr size_t OFF_MC    = 256;                             // ctrl first (256 B)
static constexpr size_t OFF_ALIST = OFF_MC + NBA * 4;
static constexpr size_t OFF_BL    = OFF_ALIST + (size_t)BB * CAP * 4;
static constexpr size_t OFF_GL    = OFF_BL + (size_t)BB * CAP * 16;
static constexpr size_t OFF_MISC  = OFF_GL + (size_t)BB * CAP * 16;
static constexpr size_t OFF_CT    = OFF_MISC + (size_t)BB * CAP * 8;
static constexpr size_t OFF_WL    = OFF_CT + (size_t)BB * GG * CAP * 4;
// total = OFF_WL + CAPW*8 ≈ 15 MB

extern "C" void kernel_launch(void* const* d_in, const int* in_sizes, int n_in,
                              void* d_out, int out_size, void* d_ws, size_t ws_size,
                              hipStream_t stream)
{
    (void)in_sizes; (void)n_in; (void)out_size; (void)ws_size;
    const float* outputs = (const float*)d_in[0];
    const float* origin  = (const float*)d_in[1];
    const float* labels  = (const float*)d_in[2];
    const float* xs_     = (const float*)d_in[3];
    const float* ys_     = (const float*)d_in[4];
    const float* st_     = (const float*)d_in[5];
    float* out = (float*)d_out;
    char* ws = (char*)d_ws;

    int*    ctrl     = (int*)(ws);
    int*    matchcnt = (int*)(ws + OFF_MC);
    int*    alist    = (int*)(ws + OFF_ALIST);
    float4* blist    = (float4*)(ws + OFF_BL);
    float4* glist    = (float4*)(ws + OFF_GL);
    float2* misc     = (float2*)(ws + OFF_MISC);
    float*  clsterm  = (float*)(ws + OFF_CT);
    int2*   wl       = (int2*)(ws + OFF_WL);

    dim3 grid1((AA + 255) / 256, BB);   // 33 x 32
    k1a_fg<<<grid1, 256, 0, stream>>>(labels, xs_, ys_, st_, ctrl, matchcnt, alist);

    dim3 grid1b(CAP / 64, BB);          // 32 x 32, blocks beyond n exit immediately
    k1b_cls<<<grid1b, 256, 0, stream>>>(outputs, labels, xs_, ys_, st_, ctrl, alist,
                                        blist, glist, misc, clsterm);

    k2_assign<<<BB * GG / 4, 256, 0, stream>>>(labels, ctrl, alist, blist, glist, clsterm,
                                               matchcnt, wl);

    k4_loss<<<K4GRID, 256, 0, stream>>>(outputs, origin, labels, xs_, ys_, st_,
                                        blist, glist, misc, clsterm, matchcnt, wl,
                                        ctrl, out);
}